// Round 1
// baseline (282.037 us; speedup 1.0000x reference)
//
#include <hip/hip_runtime.h>

// B=1048576, A=3, N=8, NUM_CLASSES=3, LAMBDA_COORD=5
#define B_SIZE 1048576

__global__ void zero_acc_kernel(double* acc) {
    if (threadIdx.x == 0 && blockIdx.x == 0) acc[0] = 0.0;
}

__global__ __launch_bounds__(256) void yolo_loss_kernel(
    const float* __restrict__ pred,       // [B,3,8]
    const float* __restrict__ gt_boxes,   // [B,8,4]
    const int*   __restrict__ gt_classes, // [B,8]
    double* __restrict__ acc) {
    const int b = blockIdx.x * 256 + threadIdx.x;  // grid covers B exactly

    // ---- vectorized loads: 24 + 32 floats + 8 ints, all consumed ----
    float pr[24];
    const float4* pv4 = reinterpret_cast<const float4*>(pred + (size_t)b * 24);
    #pragma unroll
    for (int i = 0; i < 6; ++i) reinterpret_cast<float4*>(pr)[i] = pv4[i];

    float gb[32];
    const float4* gv4 = reinterpret_cast<const float4*>(gt_boxes + (size_t)b * 32);
    #pragma unroll
    for (int i = 0; i < 8; ++i) reinterpret_cast<float4*>(gb)[i] = gv4[i];

    int gc[8];
    const int4* gc4 = reinterpret_cast<const int4*>(gt_classes + (size_t)b * 8);
    #pragma unroll
    for (int i = 0; i < 2; ++i) reinterpret_cast<int4*>(gc)[i] = gc4[i];

    float total = 0.0f;
    #pragma unroll
    for (int a = 0; a < 3; ++a) {
        const float* p = pr + a * 8;
        const float px = 1.0f / (1.0f + expf(-p[0]));
        const float py = 1.0f / (1.0f + expf(-p[1]));
        const float pw = p[2];
        const float ph = p[3];
        const float pconf = 1.0f / (1.0f + expf(-p[4]));
        const float px1 = px - pw * 0.5f, px2 = px + pw * 0.5f;
        const float py1 = py - ph * 0.5f, py2 = py + ph * 0.5f;
        const float pred_area = (px2 - px1) * (py2 - py1);

        // ---- argmax IoU over 8 gt boxes, first-max semantics, track winner ----
        float best_iou = -1e30f;
        float mbx = gb[0], mby = gb[1], mbw = gb[2], mbh = gb[3];
        int mcls = gc[0];
        #pragma unroll
        for (int n = 0; n < 8; ++n) {
            const float gx = gb[n*4+0], gy = gb[n*4+1];
            const float gw = gb[n*4+2], gh = gb[n*4+3];
            const float gx1 = gx - gw*0.5f, gx2 = gx + gw*0.5f;
            const float gy1 = gy - gh*0.5f, gy2 = gy + gh*0.5f;
            const float iw = fmaxf(fminf(px2, gx2) - fmaxf(px1, gx1), 0.0f);
            const float ih = fmaxf(fminf(py2, gy2) - fmaxf(py1, gy1), 0.0f);
            const float inter = iw * ih;
            const float gt_area = (gx2 - gx1) * (gy2 - gy1);
            const float iou = inter / (pred_area + gt_area - inter + 1e-6f);
            if (iou > best_iou) {
                best_iou = iou;
                mbx = gx; mby = gy; mbw = gw; mbh = gh; mcls = gc[n];
            }
        }
        const bool matched = best_iou > 0.5f;

        // conf loss: matched ? -log(pconf) : -log1p(-pconf), clamped at -100
        const float lp   = fmaxf(logf(pconf),    -100.0f);
        const float l1mp = fmaxf(log1pf(-pconf), -100.0f);
        total += matched ? -lp : -l1mp;

        if (matched) {
            // coord loss * LAMBDA_COORD
            const float dx = px - mbx, dy = py - mby;
            const float dw = pw - mbw, dh = ph - mbh;
            total += 5.0f * (dx*dx + dy*dy + dw*dw + dh*dh);
            // class NLL via log-softmax over 3 logits
            const float l0 = p[5], l1 = p[6], l2 = p[7];
            const float m = fmaxf(l0, fmaxf(l1, l2));
            const float lse = m + logf(expf(l0-m) + expf(l1-m) + expf(l2-m));
            const float sel = (mcls == 0) ? l0 : ((mcls == 1) ? l1 : l2);
            total += lse - sel;
        }
    }

    // ---- wave(64) shuffle reduce -> LDS -> one double atomic per block ----
    #pragma unroll
    for (int off = 32; off > 0; off >>= 1)
        total += __shfl_down(total, off, 64);
    __shared__ float smem[4];
    const int lane = threadIdx.x & 63;
    const int wid  = threadIdx.x >> 6;
    if (lane == 0) smem[wid] = total;
    __syncthreads();
    if (threadIdx.x == 0) {
        const double s = (double)smem[0] + (double)smem[1]
                       + (double)smem[2] + (double)smem[3];
        atomicAdd(acc, s);
    }
}

__global__ void finalize_kernel(const double* __restrict__ acc,
                                float* __restrict__ out) {
    if (threadIdx.x == 0 && blockIdx.x == 0)
        out[0] = (float)(acc[0] / (double)B_SIZE);
}

extern "C" void kernel_launch(void* const* d_in, const int* in_sizes, int n_in,
                              void* d_out, int out_size, void* d_ws, size_t ws_size,
                              hipStream_t stream) {
    const float* pred       = (const float*)d_in[0];
    const float* gt_boxes   = (const float*)d_in[1];
    const int*   gt_classes = (const int*)d_in[2];
    float* out = (float*)d_out;
    double* acc = (double*)d_ws;   // re-poisoned every launch -> must zero

    zero_acc_kernel<<<1, 64, 0, stream>>>(acc);
    yolo_loss_kernel<<<B_SIZE / 256, 256, 0, stream>>>(pred, gt_boxes, gt_classes, acc);
    finalize_kernel<<<1, 64, 0, stream>>>(acc, out);
}

// Round 2
// 281.360 us; speedup vs baseline: 1.0024x; 1.0024x over previous
//
#include <hip/hip_runtime.h>

// B=1048576, A=3, N=8, NUM_CLASSES=3, LAMBDA_COORD=5
#define B_SIZE 1048576

__global__ void zero_acc_kernel(double* acc) {
    if (threadIdx.x == 0 && blockIdx.x == 0) acc[0] = 0.0;
}

__device__ __forceinline__ float frcp(float x) { return __builtin_amdgcn_rcpf(x); }

__global__ __launch_bounds__(256) void yolo_loss_kernel(
    const float* __restrict__ pred,       // [B,3,8]
    const float* __restrict__ gt_boxes,   // [B,8,4]
    const int*   __restrict__ gt_classes, // [B,8]
    double* __restrict__ acc) {
    const int b = blockIdx.x * 256 + threadIdx.x;  // grid covers B exactly

    // ---- vectorized loads: 24 + 32 floats + 8 ints, all consumed ----
    float pr[24];
    const float4* pv4 = reinterpret_cast<const float4*>(pred + (size_t)b * 24);
    #pragma unroll
    for (int i = 0; i < 6; ++i) reinterpret_cast<float4*>(pr)[i] = pv4[i];

    float gb[32];
    const float4* gv4 = reinterpret_cast<const float4*>(gt_boxes + (size_t)b * 32);
    #pragma unroll
    for (int i = 0; i < 8; ++i) reinterpret_cast<float4*>(gb)[i] = gv4[i];

    int gc[8];
    const int4* gc4 = reinterpret_cast<const int4*>(gt_classes + (size_t)b * 8);
    #pragma unroll
    for (int i = 0; i < 2; ++i) reinterpret_cast<int4*>(gc)[i] = gc4[i];

    float total = 0.0f;
    #pragma unroll
    for (int a = 0; a < 3; ++a) {
        const float* p = pr + a * 8;
        // fast sigmoid: 1/(1+e^-x) via native exp + v_rcp
        const float px = frcp(1.0f + __expf(-p[0]));
        const float py = frcp(1.0f + __expf(-p[1]));
        const float pw = p[2];
        const float ph = p[3];
        const float z  = p[4];              // conf logit; sigmoid never materialized
        const float px1 = px - pw * 0.5f, px2 = px + pw * 0.5f;
        const float py1 = py - ph * 0.5f, py2 = py + ph * 0.5f;
        const float pa_eps = (px2 - px1) * (py2 - py1) + 1e-6f;

        // ---- argmax IoU over 8 gt boxes: track (best_iou, best_idx) only ----
        float best_iou = -3.4e38f;
        int best_idx = 0;
        #pragma unroll
        for (int n = 0; n < 8; ++n) {
            const float gx = gb[n*4+0], gy = gb[n*4+1];
            const float gw = gb[n*4+2], gh = gb[n*4+3];
            const float hw = gw * 0.5f, hh = gh * 0.5f;
            const float gx1 = gx - hw, gx2 = gx + hw;
            const float gy1 = gy - hh, gy2 = gy + hh;
            const float iw = fmaxf(fminf(px2, gx2) - fmaxf(px1, gx1), 0.0f);
            const float ih = fmaxf(fminf(py2, gy2) - fmaxf(py1, gy1), 0.0f);
            const float inter = iw * ih;
            const float den = (pa_eps + gw * gh) - inter;
            const float iou = inter * frcp(den);   // v_rcp instead of full divide
            const bool upd = iou > best_iou;       // strict > == first-max (argmax)
            best_iou = upd ? iou : best_iou;
            best_idx = upd ? n : best_idx;
        }
        const bool matched = best_iou > 0.5f;

        // ---- payload select tree for the winning gt box ----
        float mbx = gb[0], mby = gb[1], mbw = gb[2], mbh = gb[3];
        int mcls = gc[0];
        #pragma unroll
        for (int n = 1; n < 8; ++n) {
            const bool s = (best_idx == n);
            mbx = s ? gb[n*4+0] : mbx;
            mby = s ? gb[n*4+1] : mby;
            mbw = s ? gb[n*4+2] : mbw;
            mbh = s ? gb[n*4+3] : mbh;
            mcls = s ? gc[n] : mcls;
        }

        // ---- conf loss via shared softplus:
        //   matched:  -max(log sigmoid(z), -100)   = min(softplus(-z), 100)
        //   else:     -max(log1p(-sigmoid(z)),-100)= min(softplus( z), 100)
        const float az = fabsf(z);
        const float c  = __logf(1.0f + __expf(-az));  // ln(1+e^-|z|), shared term
        const float sp_pos = fmaxf(z, 0.0f) + c;
        const float sp_neg = fmaxf(-z, 0.0f) + c;
        total += fminf(matched ? sp_neg : sp_pos, 100.0f);

        if (matched) {
            // coord loss * LAMBDA_COORD
            const float dx = px - mbx, dy = py - mby;
            const float dw = pw - mbw, dh = ph - mbh;
            total += 5.0f * (dx*dx + dy*dy + dw*dw + dh*dh);
            // class NLL via log-softmax over 3 logits (native exp/log)
            const float l0 = p[5], l1 = p[6], l2 = p[7];
            const float m = fmaxf(l0, fmaxf(l1, l2));
            const float lse = m + __logf(__expf(l0-m) + __expf(l1-m) + __expf(l2-m));
            const float sel = (mcls == 0) ? l0 : ((mcls == 1) ? l1 : l2);
            total += lse - sel;
        }
    }

    // ---- wave(64) shuffle reduce -> LDS -> one double atomic per block ----
    #pragma unroll
    for (int off = 32; off > 0; off >>= 1)
        total += __shfl_down(total, off, 64);
    __shared__ float smem[4];
    const int lane = threadIdx.x & 63;
    const int wid  = threadIdx.x >> 6;
    if (lane == 0) smem[wid] = total;
    __syncthreads();
    if (threadIdx.x == 0) {
        const double s = (double)smem[0] + (double)smem[1]
                       + (double)smem[2] + (double)smem[3];
        atomicAdd(acc, s);
    }
}

__global__ void finalize_kernel(const double* __restrict__ acc,
                                float* __restrict__ out) {
    if (threadIdx.x == 0 && blockIdx.x == 0)
        out[0] = (float)(acc[0] / (double)B_SIZE);
}

extern "C" void kernel_launch(void* const* d_in, const int* in_sizes, int n_in,
                              void* d_out, int out_size, void* d_ws, size_t ws_size,
                              hipStream_t stream) {
    const float* pred       = (const float*)d_in[0];
    const float* gt_boxes   = (const float*)d_in[1];
    const int*   gt_classes = (const int*)d_in[2];
    float* out = (float*)d_out;
    double* acc = (double*)d_ws;   // re-poisoned every launch -> must zero

    zero_acc_kernel<<<1, 64, 0, stream>>>(acc);
    yolo_loss_kernel<<<B_SIZE / 256, 256, 0, stream>>>(pred, gt_boxes, gt_classes, acc);
    finalize_kernel<<<1, 64, 0, stream>>>(acc, out);
}

// Round 3
// 274.029 us; speedup vs baseline: 1.0292x; 1.0268x over previous
//
#include <hip/hip_runtime.h>

// B=1048576, A=3, N=8, NUM_CLASSES=3, LAMBDA_COORD=5
#define B_SIZE 1048576
#define NBLK   4096   // 256 threads/block, 64 batches/wave

__device__ __forceinline__ float frcp(float x) { return __builtin_amdgcn_rcpf(x); }

__global__ __launch_bounds__(256) void yolo_loss_kernel(
    const float* __restrict__ pred,       // [B,3,8]  row = 24 floats
    const float* __restrict__ gt_boxes,   // [B,8,4]  row = 32 floats
    const int*   __restrict__ gt_classes, // [B,8]    row = 8 ints
    double* __restrict__ part) {          // [NBLK] per-block partials (no atomics)
    // Per-wave LDS staging regions, odd-dword row strides -> conflict-free reads.
    __shared__ float sP[4][64 * 25];   // pred: 24 floats/row, pad to 25 (25.6 KB)
    __shared__ float sG[4][64 * 33];   // gt:   32 floats/row, pad to 33 (33.8 KB)
    __shared__ float sRed[4];

    const int tid  = threadIdx.x;
    const int wave = tid >> 6;
    const int lane = tid & 63;
    const int wb   = blockIdx.x * 256 + wave * 64;   // wave's batch base

    // ---- fully coalesced global loads (1 KB per wave64 instruction) ----
    const float4* pA = reinterpret_cast<const float4*>(pred     + (size_t)wb * 24);
    const float4* gA = reinterpret_cast<const float4*>(gt_boxes + (size_t)wb * 32);
    float4 vp[6], vg[8];
    #pragma unroll
    for (int k = 0; k < 6; ++k) vp[k] = pA[k * 64 + lane];
    #pragma unroll
    for (int k = 0; k < 8; ++k) vg[k] = gA[k * 64 + lane];
    // classes: tiny (32 B/row); direct per-batch loads, 2 instructions
    const int4* cme = reinterpret_cast<const int4*>(gt_classes + (size_t)(wb + lane) * 8);
    const int4 c0 = cme[0], c1 = cme[1];

    // ---- LDS transpose: linear slab -> padded per-batch rows ----
    float* sp = sP[wave];
    float* sg = sG[wave];
    #pragma unroll
    for (int k = 0; k < 6; ++k) {
        const unsigned f = k * 64 + lane;          // float4 idx in 64x6 pred slab
        const unsigned bl = f / 6u, of = f % 6u;   // magic-mul, constant divisor
        float* d = &sp[bl * 25 + of * 4];
        d[0] = vp[k].x; d[1] = vp[k].y; d[2] = vp[k].z; d[3] = vp[k].w;
    }
    #pragma unroll
    for (int k = 0; k < 8; ++k) {
        const unsigned f = k * 64 + lane;          // float4 idx in 64x8 gt slab
        const unsigned bl = f >> 3, of = f & 7;
        float* d = &sg[bl * 33 + of * 4];
        d[0] = vg[k].x; d[1] = vg[k].y; d[2] = vg[k].z; d[3] = vg[k].w;
    }
    // read own batch row back (stride 25/33 odd -> 2 lanes/bank = free)
    float pr[24];
    #pragma unroll
    for (int w = 0; w < 24; ++w) pr[w] = sp[lane * 25 + w];
    float gb[32];
    #pragma unroll
    for (int w = 0; w < 32; ++w) gb[w] = sg[lane * 33 + w];
    const int gc[8] = {c0.x, c0.y, c0.z, c0.w, c1.x, c1.y, c1.z, c1.w};

    // ---- per-anchor loss math (R2-validated) ----
    float total = 0.0f;
    #pragma unroll
    for (int a = 0; a < 3; ++a) {
        const float* p = pr + a * 8;
        const float px = frcp(1.0f + __expf(-p[0]));
        const float py = frcp(1.0f + __expf(-p[1]));
        const float pw = p[2];
        const float ph = p[3];
        const float z  = p[4];
        const float px1 = px - pw * 0.5f, px2 = px + pw * 0.5f;
        const float py1 = py - ph * 0.5f, py2 = py + ph * 0.5f;
        const float pa_eps = (px2 - px1) * (py2 - py1) + 1e-6f;

        float best_iou = -3.4e38f;
        int best_idx = 0;
        #pragma unroll
        for (int n = 0; n < 8; ++n) {
            const float gx = gb[n*4+0], gy = gb[n*4+1];
            const float gw = gb[n*4+2], gh = gb[n*4+3];
            const float hw = gw * 0.5f, hh = gh * 0.5f;
            const float iw = fmaxf(fminf(px2, gx + hw) - fmaxf(px1, gx - hw), 0.0f);
            const float ih = fmaxf(fminf(py2, gy + hh) - fmaxf(py1, gy - hh), 0.0f);
            const float inter = iw * ih;
            const float iou = inter * frcp((pa_eps + gw * gh) - inter);
            const bool upd = iou > best_iou;       // strict > == first-max (argmax)
            best_iou = upd ? iou : best_iou;
            best_idx = upd ? n : best_idx;
        }
        const bool matched = best_iou > 0.5f;

        float mbx = gb[0], mby = gb[1], mbw = gb[2], mbh = gb[3];
        int mcls = gc[0];
        #pragma unroll
        for (int n = 1; n < 8; ++n) {
            const bool s = (best_idx == n);
            mbx = s ? gb[n*4+0] : mbx;
            mby = s ? gb[n*4+1] : mby;
            mbw = s ? gb[n*4+2] : mbw;
            mbh = s ? gb[n*4+3] : mbh;
            mcls = s ? gc[n] : mcls;
        }

        // conf loss via shared softplus (clamped):
        const float az = fabsf(z);
        const float c  = __logf(1.0f + __expf(-az));
        const float sp_pos = fmaxf(z, 0.0f) + c;
        const float sp_neg = fmaxf(-z, 0.0f) + c;
        total += fminf(matched ? sp_neg : sp_pos, 100.0f);

        if (matched) {
            const float dx = px - mbx, dy = py - mby;
            const float dw = pw - mbw, dh = ph - mbh;
            total += 5.0f * (dx*dx + dy*dy + dw*dw + dh*dh);
            const float l0 = p[5], l1 = p[6], l2 = p[7];
            const float m = fmaxf(l0, fmaxf(l1, l2));
            const float lse = m + __logf(__expf(l0-m) + __expf(l1-m) + __expf(l2-m));
            const float sel = (mcls == 0) ? l0 : ((mcls == 1) ? l1 : l2);
            total += lse - sel;
        }
    }

    // ---- wave(64) shuffle reduce -> per-block partial store (NO atomics) ----
    #pragma unroll
    for (int off = 32; off > 0; off >>= 1)
        total += __shfl_down(total, off, 64);
    if (lane == 0) sRed[wave] = total;
    __syncthreads();
    if (tid == 0) {
        part[blockIdx.x] = (double)sRed[0] + (double)sRed[1]
                         + (double)sRed[2] + (double)sRed[3];
    }
}

__global__ __launch_bounds__(256) void yolo_reduce_kernel(
    const double* __restrict__ part, float* __restrict__ out) {
    double s = 0.0;
    #pragma unroll
    for (int k = 0; k < NBLK / 256; ++k)
        s += part[threadIdx.x + k * 256];      // coalesced
    #pragma unroll
    for (int off = 32; off > 0; off >>= 1)
        s += __shfl_down(s, off, 64);
    __shared__ double r[4];
    const int lane = threadIdx.x & 63;
    const int wave = threadIdx.x >> 6;
    if (lane == 0) r[wave] = s;
    __syncthreads();
    if (threadIdx.x == 0)
        out[0] = (float)((r[0] + r[1] + r[2] + r[3]) / (double)B_SIZE);
}

extern "C" void kernel_launch(void* const* d_in, const int* in_sizes, int n_in,
                              void* d_out, int out_size, void* d_ws, size_t ws_size,
                              hipStream_t stream) {
    const float* pred       = (const float*)d_in[0];
    const float* gt_boxes   = (const float*)d_in[1];
    const int*   gt_classes = (const int*)d_in[2];
    float* out   = (float*)d_out;
    double* part = (double*)d_ws;   // 4096 doubles = 32 KB scratch; every slot
                                    // written each launch (poison-safe)

    yolo_loss_kernel<<<NBLK, 256, 0, stream>>>(pred, gt_boxes, gt_classes, part);
    yolo_reduce_kernel<<<1, 256, 0, stream>>>(part, out);
}